// Round 2
// baseline (1141.777 us; speedup 1.0000x reference)
//
#include <hip/hip_runtime.h>

#define BB 2
#define SS 2048
#define DD 1024
#define HH 16
#define DHH 64

typedef float v4f __attribute__((ext_vector_type(4)));
typedef short v8s __attribute__((ext_vector_type(8)));

__device__ __forceinline__ unsigned short f2bf(float f) {
  unsigned u = __float_as_uint(f);
  u += 0x7FFFu + ((u >> 16) & 1u);
  return (unsigned short)(u >> 16);
}

// ---------------- detect mask storage format ----------------
// fmt 0: int32 (0/1), fmt 1: bool bytes (0/1), fmt 2: float32 (0.0/1.0)
__global__ void k_detect(const unsigned* mw, int* flag) {
  __shared__ unsigned red[256];
  int t = threadIdx.x;
  unsigned bits = 0;
  for (int i = t; i < 1024; i += 256) {
    unsigned w = mw[i];
    if (w & 0xFFFFFF00u) bits |= 2u;   // high bytes nonzero -> not int32 0/1
    if (w == 0x3F800000u) bits |= 1u;  // float 1.0 pattern
  }
  red[t] = bits;
  __syncthreads();
  for (int s = 128; s > 0; s >>= 1) {
    if (t < s) red[t] |= red[t + s];
    __syncthreads();
  }
  if (t == 0) {
    unsigned b = red[0];
    int fmt = 0;
    if (b & 2u) fmt = (b & 1u) ? 2 : 1;
    *flag = fmt;
  }
}

// ---------------- pack mask to bitmask ----------------
__global__ void k_pack(const void* mask, unsigned long long* packed, const int* flag) {
  int fmt = *flag;
  long long gid = (long long)blockIdx.x * 256 + threadIdx.x;
  bool pred;
  if (fmt == 0)      pred = ((const int*)mask)[gid] != 0;
  else if (fmt == 1) pred = ((const unsigned char*)mask)[gid] != 0;
  else               pred = ((const float*)mask)[gid] > 0.0f;
  unsigned long long bal = __ballot(pred);
  if ((threadIdx.x & 63) == 0) packed[gid >> 6] = bal;
}

// ---------------- W -> W^T bf16 ----------------
__global__ void k_wtrans(const float* W0, const float* W1, const float* W2, const float* W3,
                         unsigned short* WT) {
  const float* W = blockIdx.z == 0 ? W0 : blockIdx.z == 1 ? W1 : blockIdx.z == 2 ? W2 : W3;
  unsigned short* o = WT + (size_t)blockIdx.z * DD * DD;
  __shared__ float tile[32][33];
  int x = threadIdx.x, y = threadIdx.y;
  int n0 = blockIdx.x * 32, k0 = blockIdx.y * 32;
#pragma unroll
  for (int j = 0; j < 4; ++j)
    tile[y + 8 * j][x] = W[(size_t)(k0 + y + 8 * j) * DD + n0 + x];
  __syncthreads();
#pragma unroll
  for (int j = 0; j < 4; ++j)
    o[(size_t)(n0 + y + 8 * j) * DD + k0 + x] = f2bf(tile[x][y + 8 * j]);
}

// ---------------- QKV projection GEMM: [4096x1024] fp32 @ WT bf16 -> heads bf16 ----------------
__launch_bounds__(256)
__global__ void k_proj(const float* Q, const float* K, const float* V,
                       const unsigned short* WT,
                       const float* bq, const float* bk, const float* bv,
                       unsigned short* qh, unsigned short* kh, unsigned short* vh) {
  int z = blockIdx.z;
  const float* X = z == 0 ? Q : z == 1 ? K : V;
  const unsigned short* Wt = WT + (size_t)z * DD * DD;
  const float* bias = z == 0 ? bq : z == 1 ? bk : bv;
  unsigned short* out = z == 0 ? qh : z == 1 ? kh : vh;

  __shared__ __align__(16) char As[128 * 32 * 2];
  __shared__ __align__(16) char Bs[128 * 32 * 2];

  int tid = threadIdx.x;
  int lane = tid & 63, wv = tid >> 6;
  int wr = wv >> 1, wc = wv & 1;
  int g = lane >> 4, r = lane & 15;

  v4f vz = {0.f, 0.f, 0.f, 0.f};
  v4f acc[4][4];
#pragma unroll
  for (int m = 0; m < 4; ++m)
#pragma unroll
    for (int n = 0; n < 4; ++n) acc[m][n] = vz;

  int srow = tid >> 1;
  int shalf = tid & 1;
  const float* aptr = X + (size_t)(blockIdx.x * 128 + srow) * DD + shalf * 16;
  const unsigned short* bptr = Wt + (size_t)(blockIdx.y * 128 + srow) * DD + shalf * 16;
  unsigned sbase = srow * 64 + shalf * 32;
  unsigned sxor = (srow & 7) << 4;

  for (int k0 = 0; k0 < DD; k0 += 32) {
    const float4* a4 = (const float4*)(aptr + k0);
    float4 f0 = a4[0], f1 = a4[1], f2 = a4[2], f3 = a4[3];
    v8s pa0, pa1;
    pa0[0] = (short)f2bf(f0.x); pa0[1] = (short)f2bf(f0.y);
    pa0[2] = (short)f2bf(f0.z); pa0[3] = (short)f2bf(f0.w);
    pa0[4] = (short)f2bf(f1.x); pa0[5] = (short)f2bf(f1.y);
    pa0[6] = (short)f2bf(f1.z); pa0[7] = (short)f2bf(f1.w);
    pa1[0] = (short)f2bf(f2.x); pa1[1] = (short)f2bf(f2.y);
    pa1[2] = (short)f2bf(f2.z); pa1[3] = (short)f2bf(f2.w);
    pa1[4] = (short)f2bf(f3.x); pa1[5] = (short)f2bf(f3.y);
    pa1[6] = (short)f2bf(f3.z); pa1[7] = (short)f2bf(f3.w);
    v8s pb0 = *(const v8s*)(bptr + k0);
    v8s pb1 = *(const v8s*)(bptr + k0 + 8);
    __syncthreads();
    *(v8s*)(As + ((sbase + 0) ^ sxor)) = pa0;
    *(v8s*)(As + ((sbase + 16) ^ sxor)) = pa1;
    *(v8s*)(Bs + ((sbase + 0) ^ sxor)) = pb0;
    *(v8s*)(Bs + ((sbase + 16) ^ sxor)) = pb1;
    __syncthreads();
    v8s af[4], bf_[4];
#pragma unroll
    for (int m = 0; m < 4; ++m) {
      int row = wr * 64 + m * 16 + r;
      af[m] = *(const v8s*)(As + ((row * 64 + g * 16) ^ ((r & 7) << 4)));
    }
#pragma unroll
    for (int n = 0; n < 4; ++n) {
      int row = wc * 64 + n * 16 + r;
      bf_[n] = *(const v8s*)(Bs + ((row * 64 + g * 16) ^ ((r & 7) << 4)));
    }
#pragma unroll
    for (int m = 0; m < 4; ++m)
#pragma unroll
      for (int n = 0; n < 4; ++n)
        acc[m][n] = __builtin_amdgcn_mfma_f32_16x16x32_bf16(af[m], bf_[n], acc[m][n], 0, 0, 0);
  }

#pragma unroll
  for (int n = 0; n < 4; ++n) {
    int nglob = blockIdx.y * 128 + wc * 64 + n * 16 + r;
    float bsv = bias[nglob];
    int h = nglob >> 6, dh = nglob & 63;
#pragma unroll
    for (int m = 0; m < 4; ++m) {
#pragma unroll
      for (int i = 0; i < 4; ++i) {
        int mglob = blockIdx.x * 128 + wr * 64 + m * 16 + g * 4 + i;
        int b = mglob >> 11, s = mglob & 2047;
        out[(((size_t)(b * HH + h) * SS + s) << 6) + dh] = f2bf(acc[m][n][i] + bsv);
      }
    }
  }
}

// ---------------- fused attention: scores + mask + softmax + soft_mat write + PV ----------------
__launch_bounds__(512)
__global__ void k_attn(const unsigned short* qh, const unsigned short* kh,
                       const unsigned short* vh, const unsigned* packed,
                       float* soft_out, unsigned short* attn_out) {
  // LDS layout (bytes):
  //   [0, 131072)        : scores fp32 [16][2048]      (phase A/B)
  //   [0, 65536)         : P bf16 [16][2048], XOR-swz  (phase C, overwrites sc rows 0-7)
  //   [65536, 81920)     : partials fp32 [8][2][16][16] (phase D)
  //   [131072, 148480)   : Vt bf16 [64][136]           (phase C V chunk, transposed)
  __shared__ __align__(16) char smem[148480];
  float* sc = (float*)smem;
  float* part = (float*)(smem + 65536);
  unsigned short* Vt = (unsigned short*)(smem + 131072);

  int tid = threadIdx.x;
  int lane = tid & 63, wv = tid >> 6;
  int g = lane >> 4, r = lane & 15;
  int qb = blockIdx.x, h = blockIdx.y, b = blockIdx.z;
  int qbase = qb << 4;
  size_t hoff = ((size_t)(b * HH + h)) * SS * DHH;
  const unsigned short* qp = qh + hoff;
  const unsigned short* kp = kh + hoff;
  const unsigned short* vp = vh + hoff;

  // ---- Phase A: scores = q @ k^T into LDS fp32 ----
  v8s aq[2];
#pragma unroll
  for (int ks = 0; ks < 2; ++ks)
    aq[ks] = *(const v8s*)(qp + (size_t)(qbase + r) * 64 + ks * 32 + g * 8);
  int n0w = wv << 8;
  for (int nt = 0; nt < 16; ++nt) {
    int n0 = n0w + (nt << 4);
    v4f acc = {0.f, 0.f, 0.f, 0.f};
#pragma unroll
    for (int ks = 0; ks < 2; ++ks) {
      v8s bfr = *(const v8s*)(kp + (size_t)(n0 + r) * 64 + ks * 32 + g * 8);
      acc = __builtin_amdgcn_mfma_f32_16x16x32_bf16(aq[ks], bfr, acc, 0, 0, 0);
    }
#pragma unroll
    for (int i = 0; i < 4; ++i)
      sc[(g * 4 + i) * 2048 + n0 + r] = acc[i];
  }
  __syncthreads();

  // ---- Phase B: mask + softmax (wave wv owns rows 2wv, 2wv+1), write probs to global ----
  float4 e[2][8];
  float inv[2];
#pragma unroll
  for (int rr = 0; rr < 2; ++rr) {
    int row = wv * 2 + rr;
    const unsigned* mrow = packed + ((size_t)b * SS + qbase + row) * 64;
    float4 s4[8];
    float mx = -3.0e38f;
#pragma unroll
    for (int j = 0; j < 8; ++j) {
      int ki = j * 256 + lane * 4;
      float4 v = *(const float4*)(sc + row * 2048 + ki);
      unsigned w = mrow[8 * j + (lane >> 3)];
      unsigned sh = (lane & 7) * 4;
      v.x = ((w >> (sh + 0)) & 1u) ? -1e9f : v.x * 0.125f;
      v.y = ((w >> (sh + 1)) & 1u) ? -1e9f : v.y * 0.125f;
      v.z = ((w >> (sh + 2)) & 1u) ? -1e9f : v.z * 0.125f;
      v.w = ((w >> (sh + 3)) & 1u) ? -1e9f : v.w * 0.125f;
      s4[j] = v;
      mx = fmaxf(mx, fmaxf(fmaxf(v.x, v.y), fmaxf(v.z, v.w)));
    }
#pragma unroll
    for (int off = 32; off >= 1; off >>= 1)
      mx = fmaxf(mx, __shfl_xor(mx, off));
    float sum = 0.f;
#pragma unroll
    for (int j = 0; j < 8; ++j) {
      float4 ev;
      ev.x = __expf(s4[j].x - mx);
      ev.y = __expf(s4[j].y - mx);
      ev.z = __expf(s4[j].z - mx);
      ev.w = __expf(s4[j].w - mx);
      e[rr][j] = ev;
      sum += (ev.x + ev.y) + (ev.z + ev.w);
    }
#pragma unroll
    for (int off = 32; off >= 1; off >>= 1)
      sum += __shfl_xor(sum, off);
    float iv = 1.0f / sum;
    inv[rr] = iv;
    float* op = soft_out + ((size_t)(b * HH + h) * SS + qbase + row) * SS;
#pragma unroll
    for (int j = 0; j < 8; ++j) {
      float4 pv;
      pv.x = e[rr][j].x * iv;
      pv.y = e[rr][j].y * iv;
      pv.z = e[rr][j].z * iv;
      pv.w = e[rr][j].w * iv;
      *(float4*)(op + j * 256 + lane * 4) = pv;
    }
  }
  __syncthreads();

  // ---- write P bf16 into [0,64K), XOR-swizzled ----
#pragma unroll
  for (int rr = 0; rr < 2; ++rr) {
    int row = wv * 2 + rr;
    float iv = inv[rr];
    unsigned rx = (row & 7) << 4;
#pragma unroll
    for (int j = 0; j < 8; ++j) {
      int ki = j * 256 + lane * 4;
      ushort4 pk;
      pk.x = f2bf(e[rr][j].x * iv);
      pk.y = f2bf(e[rr][j].y * iv);
      pk.z = f2bf(e[rr][j].z * iv);
      pk.w = f2bf(e[rr][j].w * iv);
      *(ushort4*)(smem + ((unsigned)(row * 4096 + ki * 2) ^ rx)) = pk;
    }
  }

  // ---- Phase C: attn = P @ V, V staged transposed in LDS per 128-row chunk ----
  int ksw = wv & 3, ng = wv >> 2;
  v4f vz = {0.f, 0.f, 0.f, 0.f};
  v4f pacc[2];
  pacc[0] = vz; pacc[1] = vz;
  int vr = tid >> 2;
  int vd0 = (tid & 3) << 4;
  for (int c = 0; c < 16; ++c) {
    __syncthreads();
    const unsigned short* vsrc = vp + (size_t)(c * 128 + vr) * 64 + vd0;
    v8s v0 = *(const v8s*)(vsrc);
    v8s v1 = *(const v8s*)(vsrc + 8);
#pragma unroll
    for (int i = 0; i < 8; ++i) Vt[(vd0 + i) * 136 + vr] = (unsigned short)v0[i];
#pragma unroll
    for (int i = 0; i < 8; ++i) Vt[(vd0 + 8 + i) * 136 + vr] = (unsigned short)v1[i];
    __syncthreads();
    unsigned paddr = (unsigned)(r * 4096 + c * 256 + ksw * 64 + g * 16);
    paddr ^= (unsigned)((r & 7) << 4);
    v8s pa = *(const v8s*)(smem + paddr);
#pragma unroll
    for (int t = 0; t < 2; ++t) {
      int n = ((ng * 2 + t) << 4) + r;
      v8s vb = *(const v8s*)(Vt + n * 136 + ksw * 32 + g * 8);
      pacc[t] = __builtin_amdgcn_mfma_f32_16x16x32_bf16(pa, vb, pacc[t], 0, 0, 0);
    }
  }

  // ---- Phase D: cross-wave K-split reduction, write attn (concat layout) bf16 ----
#pragma unroll
  for (int t = 0; t < 2; ++t)
#pragma unroll
    for (int i = 0; i < 4; ++i)
      part[((wv * 2 + t) * 16 + g * 4 + i) * 16 + r] = pacc[t][i];
  __syncthreads();
  for (int o = tid; o < 1024; o += 512) {
    int m = o >> 6, col = o & 63;
    int grp = col >> 5, tt = (col >> 4) & 1, cc = col & 15;
    float v = 0.f;
#pragma unroll
    for (int k4 = 0; k4 < 4; ++k4)
      v += part[(((grp * 4 + k4) * 2 + tt) * 16 + m) * 16 + cc];
    attn_out[((size_t)b * SS + qbase + m) * DD + (h << 6) + col] = f2bf(v);
  }
}

// ---------------- output projection: attn bf16 @ WoT + bo -> fp32 ----------------
__launch_bounds__(256)
__global__ void k_oproj(const unsigned short* A, const unsigned short* WT4,
                        const float* bo, float* out) {
  const unsigned short* Wt = WT4 + (size_t)3 * DD * DD;
  __shared__ __align__(16) char As[128 * 32 * 2];
  __shared__ __align__(16) char Bs[128 * 32 * 2];

  int tid = threadIdx.x;
  int lane = tid & 63, wv = tid >> 6;
  int wr = wv >> 1, wc = wv & 1;
  int g = lane >> 4, r = lane & 15;

  v4f vz = {0.f, 0.f, 0.f, 0.f};
  v4f acc[4][4];
#pragma unroll
  for (int m = 0; m < 4; ++m)
#pragma unroll
    for (int n = 0; n < 4; ++n) acc[m][n] = vz;

  int srow = tid >> 1;
  int shalf = tid & 1;
  const unsigned short* aptr = A + (size_t)(blockIdx.x * 128 + srow) * DD + shalf * 16;
  const unsigned short* bptr = Wt + (size_t)(blockIdx.y * 128 + srow) * DD + shalf * 16;
  unsigned sbase = srow * 64 + shalf * 32;
  unsigned sxor = (srow & 7) << 4;

  for (int k0 = 0; k0 < DD; k0 += 32) {
    v8s pa0 = *(const v8s*)(aptr + k0);
    v8s pa1 = *(const v8s*)(aptr + k0 + 8);
    v8s pb0 = *(const v8s*)(bptr + k0);
    v8s pb1 = *(const v8s*)(bptr + k0 + 8);
    __syncthreads();
    *(v8s*)(As + ((sbase + 0) ^ sxor)) = pa0;
    *(v8s*)(As + ((sbase + 16) ^ sxor)) = pa1;
    *(v8s*)(Bs + ((sbase + 0) ^ sxor)) = pb0;
    *(v8s*)(Bs + ((sbase + 16) ^ sxor)) = pb1;
    __syncthreads();
    v8s af[4], bf_[4];
#pragma unroll
    for (int m = 0; m < 4; ++m) {
      int row = wr * 64 + m * 16 + r;
      af[m] = *(const v8s*)(As + ((row * 64 + g * 16) ^ ((r & 7) << 4)));
    }
#pragma unroll
    for (int n = 0; n < 4; ++n) {
      int row = wc * 64 + n * 16 + r;
      bf_[n] = *(const v8s*)(Bs + ((row * 64 + g * 16) ^ ((r & 7) << 4)));
    }
#pragma unroll
    for (int m = 0; m < 4; ++m)
#pragma unroll
      for (int n = 0; n < 4; ++n)
        acc[m][n] = __builtin_amdgcn_mfma_f32_16x16x32_bf16(af[m], bf_[n], acc[m][n], 0, 0, 0);
  }

#pragma unroll
  for (int n = 0; n < 4; ++n) {
    int nglob = blockIdx.y * 128 + wc * 64 + n * 16 + r;
    float bsv = bo[nglob];
#pragma unroll
    for (int m = 0; m < 4; ++m) {
#pragma unroll
      for (int i = 0; i < 4; ++i) {
        int mglob = blockIdx.x * 128 + wr * 64 + m * 16 + g * 4 + i;
        out[(size_t)mglob * DD + nglob] = acc[m][n][i] + bsv;
      }
    }
  }
}

extern "C" void kernel_launch(void* const* d_in, const int* in_sizes, int n_in,
                              void* d_out, int out_size, void* d_ws, size_t ws_size,
                              hipStream_t stream) {
  (void)in_sizes; (void)n_in; (void)out_size; (void)ws_size;
  const float* Q  = (const float*)d_in[0];
  const float* K  = (const float*)d_in[1];
  const float* V  = (const float*)d_in[2];
  const void*  M  = d_in[3];
  const float* Wq = (const float*)d_in[4];
  const float* bq = (const float*)d_in[5];
  const float* Wk = (const float*)d_in[6];
  const float* bk = (const float*)d_in[7];
  const float* Wv = (const float*)d_in[8];
  const float* bv = (const float*)d_in[9];
  const float* Wo = (const float*)d_in[10];
  const float* bo = (const float*)d_in[11];

  float* out  = (float*)d_out;
  float* soft = out + (size_t)BB * SS * DD;

  char* ws = (char*)d_ws;
  int* flag = (int*)ws;
  unsigned long long* packed = (unsigned long long*)(ws + 256);             // 1 MB
  unsigned short* WT   = (unsigned short*)(ws + 256 + 1048576);             // 8 MB (4x D*D bf16)
  unsigned short* qhp  = (unsigned short*)(ws + 256 + 1048576 + 8388608);   // 8 MB
  unsigned short* khp  = qhp + (size_t)BB * SS * DD;                        // 8 MB
  unsigned short* vhp  = khp + (size_t)BB * SS * DD;                        // 8 MB
  unsigned short* attn = vhp + (size_t)BB * SS * DD;                        // 8 MB

  k_detect<<<1, 256, 0, stream>>>((const unsigned*)M, flag);
  k_pack<<<BB * SS * SS / 256, 256, 0, stream>>>(M, packed, flag);
  k_wtrans<<<dim3(32, 32, 4), dim3(32, 8), 0, stream>>>(Wq, Wk, Wv, Wo, WT);
  k_proj<<<dim3(32, 8, 3), 256, 0, stream>>>(Q, K, V, WT, bq, bk, bv, qhp, khp, vhp);
  k_attn<<<dim3(SS / 16, HH, BB), 512, 0, stream>>>(qhp, khp, vhp, (const unsigned*)packed, soft, attn);
  k_oproj<<<dim3(32, 8), 256, 0, stream>>>(attn, WT, bo, out);
}

// Round 4
// 1011.333 us; speedup vs baseline: 1.1290x; 1.1290x over previous
//
#include <hip/hip_runtime.h>

#define BB 2
#define SS 2048
#define DD 1024
#define HH 16
#define DHH 64

typedef float v4f __attribute__((ext_vector_type(4)));
typedef short v8s __attribute__((ext_vector_type(8)));

__device__ __forceinline__ unsigned short f2bf(float f) {
  unsigned u = __float_as_uint(f);
  u += 0x7FFFu + ((u >> 16) & 1u);
  return (unsigned short)(u >> 16);
}

// ---------------- detect mask storage format ----------------
__global__ void k_detect(const unsigned* mw, int* flag) {
  __shared__ unsigned red[256];
  int t = threadIdx.x;
  unsigned bits = 0;
  for (int i = t; i < 1024; i += 256) {
    unsigned w = mw[i];
    if (w & 0xFFFFFF00u) bits |= 2u;
    if (w == 0x3F800000u) bits |= 1u;
  }
  red[t] = bits;
  __syncthreads();
  for (int s = 128; s > 0; s >>= 1) {
    if (t < s) red[t] |= red[t + s];
    __syncthreads();
  }
  if (t == 0) {
    unsigned b = red[0];
    int fmt = 0;
    if (b & 2u) fmt = (b & 1u) ? 2 : 1;
    *flag = fmt;
  }
}

// ---------------- pack mask to bitmask ----------------
__global__ void k_pack(const void* mask, unsigned long long* packed, const int* flag) {
  int fmt = *flag;
  long long gid = (long long)blockIdx.x * 256 + threadIdx.x;
  bool pred;
  if (fmt == 0)      pred = ((const int*)mask)[gid] != 0;
  else if (fmt == 1) pred = ((const unsigned char*)mask)[gid] != 0;
  else               pred = ((const float*)mask)[gid] > 0.0f;
  unsigned long long bal = __ballot(pred);
  if ((threadIdx.x & 63) == 0) packed[gid >> 6] = bal;
}

// ---------------- W -> W^T bf16 ----------------
__global__ void k_wtrans(const float* W0, const float* W1, const float* W2, const float* W3,
                         unsigned short* WT) {
  const float* W = blockIdx.z == 0 ? W0 : blockIdx.z == 1 ? W1 : blockIdx.z == 2 ? W2 : W3;
  unsigned short* o = WT + (size_t)blockIdx.z * DD * DD;
  __shared__ float tile[32][33];
  int x = threadIdx.x, y = threadIdx.y;
  int n0 = blockIdx.x * 32, k0 = blockIdx.y * 32;
#pragma unroll
  for (int j = 0; j < 4; ++j)
    tile[y + 8 * j][x] = W[(size_t)(k0 + y + 8 * j) * DD + n0 + x];
  __syncthreads();
#pragma unroll
  for (int j = 0; j < 4; ++j)
    o[(size_t)(n0 + y + 8 * j) * DD + k0 + x] = f2bf(tile[x][y + 8 * j]);
}

// ---------------- QKV projection GEMM ----------------
// z==0 -> qh [bh][s][dh], z==1 -> kh [bh][s][dh], z==2 -> vhT [bh][dh][s] (transposed!)
__launch_bounds__(256)
__global__ void k_proj(const float* Q, const float* K, const float* V,
                       const unsigned short* WT,
                       const float* bq, const float* bk, const float* bv,
                       unsigned short* qh, unsigned short* kh, unsigned short* vhT) {
  int z = blockIdx.z;
  const float* X = z == 0 ? Q : z == 1 ? K : V;
  const unsigned short* Wt = WT + (size_t)z * DD * DD;
  const float* bias = z == 0 ? bq : z == 1 ? bk : bv;
  unsigned short* out = z == 0 ? qh : z == 1 ? kh : vhT;

  __shared__ __align__(16) char As[128 * 32 * 2];
  __shared__ __align__(16) char Bs[128 * 32 * 2];

  int tid = threadIdx.x;
  int lane = tid & 63, wv = tid >> 6;
  int wr = wv >> 1, wc = wv & 1;
  int g = lane >> 4, r = lane & 15;

  v4f vz = {0.f, 0.f, 0.f, 0.f};
  v4f acc[4][4];
#pragma unroll
  for (int m = 0; m < 4; ++m)
#pragma unroll
    for (int n = 0; n < 4; ++n) acc[m][n] = vz;

  int srow = tid >> 1;
  int shalf = tid & 1;
  const float* aptr = X + (size_t)(blockIdx.x * 128 + srow) * DD + shalf * 16;
  const unsigned short* bptr = Wt + (size_t)(blockIdx.y * 128 + srow) * DD + shalf * 16;
  unsigned sbase = srow * 64 + shalf * 32;
  unsigned sxor = (srow & 7) << 4;

  for (int k0 = 0; k0 < DD; k0 += 32) {
    const float4* a4 = (const float4*)(aptr + k0);
    float4 f0 = a4[0], f1 = a4[1], f2 = a4[2], f3 = a4[3];
    v8s pa0, pa1;
    pa0[0] = (short)f2bf(f0.x); pa0[1] = (short)f2bf(f0.y);
    pa0[2] = (short)f2bf(f0.z); pa0[3] = (short)f2bf(f0.w);
    pa0[4] = (short)f2bf(f1.x); pa0[5] = (short)f2bf(f1.y);
    pa0[6] = (short)f2bf(f1.z); pa0[7] = (short)f2bf(f1.w);
    pa1[0] = (short)f2bf(f2.x); pa1[1] = (short)f2bf(f2.y);
    pa1[2] = (short)f2bf(f2.z); pa1[3] = (short)f2bf(f2.w);
    pa1[4] = (short)f2bf(f3.x); pa1[5] = (short)f2bf(f3.y);
    pa1[6] = (short)f2bf(f3.z); pa1[7] = (short)f2bf(f3.w);
    v8s pb0 = *(const v8s*)(bptr + k0);
    v8s pb1 = *(const v8s*)(bptr + k0 + 8);
    __syncthreads();
    *(v8s*)(As + ((sbase + 0) ^ sxor)) = pa0;
    *(v8s*)(As + ((sbase + 16) ^ sxor)) = pa1;
    *(v8s*)(Bs + ((sbase + 0) ^ sxor)) = pb0;
    *(v8s*)(Bs + ((sbase + 16) ^ sxor)) = pb1;
    __syncthreads();
    v8s af[4], bf_[4];
#pragma unroll
    for (int m = 0; m < 4; ++m) {
      int row = wr * 64 + m * 16 + r;
      af[m] = *(const v8s*)(As + ((row * 64 + g * 16) ^ ((r & 7) << 4)));
    }
#pragma unroll
    for (int n = 0; n < 4; ++n) {
      int row = wc * 64 + n * 16 + r;
      bf_[n] = *(const v8s*)(Bs + ((row * 64 + g * 16) ^ ((r & 7) << 4)));
    }
#pragma unroll
    for (int m = 0; m < 4; ++m)
#pragma unroll
      for (int n = 0; n < 4; ++n)
        acc[m][n] = __builtin_amdgcn_mfma_f32_16x16x32_bf16(af[m], bf_[n], acc[m][n], 0, 0, 0);
  }

  if (z == 2) {
    // transposed write: vhT[(bh*64 + dh)*2048 + s], 4 consecutive s -> ushort4
#pragma unroll
    for (int n = 0; n < 4; ++n) {
      int nglob = blockIdx.y * 128 + wc * 64 + n * 16 + r;
      float bsv = bias[nglob];
      int h = nglob >> 6, dh = nglob & 63;
#pragma unroll
      for (int m = 0; m < 4; ++m) {
        int mg0 = blockIdx.x * 128 + wr * 64 + m * 16 + g * 4;
        int b0 = mg0 >> 11, s0 = mg0 & 2047;
        ushort4 pk;
        pk.x = f2bf(acc[m][n][0] + bsv);
        pk.y = f2bf(acc[m][n][1] + bsv);
        pk.z = f2bf(acc[m][n][2] + bsv);
        pk.w = f2bf(acc[m][n][3] + bsv);
        *(ushort4*)(out + ((size_t)(b0 * HH + h) * DHH + dh) * SS + s0) = pk;
      }
    }
  } else {
#pragma unroll
    for (int n = 0; n < 4; ++n) {
      int nglob = blockIdx.y * 128 + wc * 64 + n * 16 + r;
      float bsv = bias[nglob];
      int h = nglob >> 6, dh = nglob & 63;
#pragma unroll
      for (int m = 0; m < 4; ++m) {
#pragma unroll
        for (int i = 0; i < 4; ++i) {
          int mglob = blockIdx.x * 128 + wr * 64 + m * 16 + g * 4 + i;
          int b0 = mglob >> 11, s0 = mglob & 2047;
          out[(((size_t)(b0 * HH + h) * SS + s0) << 6) + dh] = f2bf(acc[m][n][i] + bsv);
        }
      }
    }
  }
}

// ---------------- fused attention v2: register S^T + softmax + probs + PV ----------------
// Per block: 16 q-rows, one (b,h). 8 waves; wave wv owns kv slice [wv*256, wv*256+256).
__launch_bounds__(512, 4)
__global__ void k_attn(const unsigned short* qh, const unsigned short* kh,
                       const unsigned short* vhT, const unsigned* packed,
                       float* soft_out, unsigned short* attn_out) {
  __shared__ __align__(16) char Pb[65536];      // P bf16 [16 q][2048 kv], XOR-swizzled
  __shared__ float red[2][8][16];               // softmax cross-wave partials
  __shared__ float red2[4][16][16];             // PV k-half reduction

  int tid = threadIdx.x;
  int lane = tid & 63, wv = tid >> 6;
  int g = lane >> 4, r = lane & 15;
  int qb = blockIdx.x, h = blockIdx.y, b = blockIdx.z;
  int qbase = qb << 4;
  int bh = b * HH + h;
  size_t hoff = (size_t)bh * SS * DHH;
  const unsigned short* qp = qh + hoff;
  const unsigned short* kp = kh + hoff;
  int n0w = wv << 8;

  // B-fragments from Q rows (col = q = r)
  v8s bqf[2];
#pragma unroll
  for (int ks = 0; ks < 2; ++ks)
    bqf[ks] = *(const v8s*)(qp + (size_t)(qbase + r) * 64 + ks * 32 + g * 8);

  // S^T tiles in registers: acc[nt][i] = score(q=r, kv = n0w + nt*16 + g*4 + i)
  v4f acc[16];
#pragma unroll
  for (int nt = 0; nt < 16; ++nt) {
    const unsigned short* krow = kp + (size_t)(n0w + nt * 16 + r) * 64;
    v4f a = {0.f, 0.f, 0.f, 0.f};
#pragma unroll
    for (int ks = 0; ks < 2; ++ks) {
      v8s av = *(const v8s*)(krow + ks * 32 + g * 8);
      a = __builtin_amdgcn_mfma_f32_16x16x32_bf16(av, bqf[ks], a, 0, 0, 0);
    }
    acc[nt] = a;
  }

  // mask words for row q = r, kv slice [n0w, n0w+256)
  const uint4* mb = (const uint4*)((const char*)packed + ((size_t)b * SS + qbase + r) * 256 + wv * 32);
  uint4 mAw = mb[0], mBw = mb[1];
  unsigned w8[8] = {mAw.x, mAw.y, mAw.z, mAw.w, mBw.x, mBw.y, mBw.z, mBw.w};

  // mask + scale, in-lane max
  float mx = -3.0e38f;
#pragma unroll
  for (int nt = 0; nt < 16; ++nt) {
    unsigned w = w8[nt >> 1];
    unsigned sh0 = (nt & 1) * 16 + g * 4;
#pragma unroll
    for (int i = 0; i < 4; ++i) {
      float s = ((w >> (sh0 + i)) & 1u) ? -1e9f : acc[nt][i] * 0.125f;
      acc[nt][i] = s;
      mx = fmaxf(mx, s);
    }
  }
  mx = fmaxf(mx, __shfl_xor(mx, 16));
  mx = fmaxf(mx, __shfl_xor(mx, 32));
  if (lane < 16) red[0][wv][lane] = mx;
  __syncthreads();
  float gmx = red[0][0][r];
#pragma unroll
  for (int j = 1; j < 8; ++j) gmx = fmaxf(gmx, red[0][j][r]);

  // exp + in-lane sum
  float sum = 0.f;
#pragma unroll
  for (int nt = 0; nt < 16; ++nt) {
#pragma unroll
    for (int i = 0; i < 4; ++i) {
      float e = __expf(acc[nt][i] - gmx);
      acc[nt][i] = e;
      sum += e;
    }
  }
  sum += __shfl_xor(sum, 16);
  sum += __shfl_xor(sum, 32);
  if (lane < 16) red[1][wv][lane] = sum;
  __syncthreads();
  float gs = 0.f;
#pragma unroll
  for (int j = 0; j < 8; ++j) gs += red[1][j][r];
  float inv = 1.0f / gs;

  // probs: float4 to global + bf16 pairs to swizzled LDS
  float* op = soft_out + ((size_t)bh * SS + qbase + r) * SS + n0w;
#pragma unroll
  for (int nt = 0; nt < 16; ++nt) {
    float4 pv;
    pv.x = acc[nt][0] * inv;
    pv.y = acc[nt][1] * inv;
    pv.z = acc[nt][2] * inv;
    pv.w = acc[nt][3] * inv;
    *(float4*)(op + nt * 16 + g * 4) = pv;
    unsigned lo = ((unsigned)f2bf(pv.y) << 16) | (unsigned)f2bf(pv.x);
    unsigned hi = ((unsigned)f2bf(pv.w) << 16) | (unsigned)f2bf(pv.z);
    unsigned addr = (unsigned)(r * 4096 + (n0w + nt * 16 + g * 4) * 2) ^ ((unsigned)(r & 7) << 4);
    *(uint2*)(Pb + addr) = make_uint2(lo, hi);
  }
  __syncthreads();

  // PV: wave -> (d-tile ng, k-half hf); B-frags straight from global vhT (L2-hot)
  int ng = wv & 3, hf = wv >> 2;
  const unsigned short* vt = vhT + ((size_t)bh * DHH + ng * 16 + r) * SS;
  v4f pacc = {0.f, 0.f, 0.f, 0.f};
#pragma unroll 4
  for (int c = 0; c < 32; ++c) {
    int kb = hf * 1024 + c * 32;
    unsigned paddr = (unsigned)(r * 4096 + kb * 2 + g * 16) ^ ((unsigned)(r & 7) << 4);
    v8s pa = *(const v8s*)(Pb + paddr);
    v8s vb = *(const v8s*)(vt + kb + g * 8);
    pacc = __builtin_amdgcn_mfma_f32_16x16x32_bf16(pa, vb, pacc, 0, 0, 0);
  }

  if (hf) {
#pragma unroll
    for (int i = 0; i < 4; ++i) red2[ng][g * 4 + i][r] = pacc[i];
  }
  __syncthreads();
  if (!hf) {
#pragma unroll
    for (int i = 0; i < 4; ++i) {
      float s = pacc[i] + red2[ng][g * 4 + i][r];
      attn_out[((size_t)b * SS + qbase + g * 4 + i) * DD + h * 64 + ng * 16 + r] = f2bf(s);
    }
  }
}

// ---------------- output projection: attn bf16 @ WoT + bo -> fp32 ----------------
__launch_bounds__(256)
__global__ void k_oproj(const unsigned short* A, const unsigned short* WT4,
                        const float* bo, float* out) {
  const unsigned short* Wt = WT4 + (size_t)3 * DD * DD;
  __shared__ __align__(16) char As[128 * 32 * 2];
  __shared__ __align__(16) char Bs[128 * 32 * 2];

  int tid = threadIdx.x;
  int lane = tid & 63, wv = tid >> 6;
  int wr = wv >> 1, wc = wv & 1;
  int g = lane >> 4, r = lane & 15;

  v4f vz = {0.f, 0.f, 0.f, 0.f};
  v4f acc[4][4];
#pragma unroll
  for (int m = 0; m < 4; ++m)
#pragma unroll
    for (int n = 0; n < 4; ++n) acc[m][n] = vz;

  int srow = tid >> 1;
  int shalf = tid & 1;
  const unsigned short* aptr = A + (size_t)(blockIdx.x * 128 + srow) * DD + shalf * 16;
  const unsigned short* bptr = Wt + (size_t)(blockIdx.y * 128 + srow) * DD + shalf * 16;
  unsigned sbase = srow * 64 + shalf * 32;
  unsigned sxor = (srow & 7) << 4;

  for (int k0 = 0; k0 < DD; k0 += 32) {
    v8s pa0 = *(const v8s*)(aptr + k0);
    v8s pa1 = *(const v8s*)(aptr + k0 + 8);
    v8s pb0 = *(const v8s*)(bptr + k0);
    v8s pb1 = *(const v8s*)(bptr + k0 + 8);
    __syncthreads();
    *(v8s*)(As + ((sbase + 0) ^ sxor)) = pa0;
    *(v8s*)(As + ((sbase + 16) ^ sxor)) = pa1;
    *(v8s*)(Bs + ((sbase + 0) ^ sxor)) = pb0;
    *(v8s*)(Bs + ((sbase + 16) ^ sxor)) = pb1;
    __syncthreads();
    v8s af[4], bf_[4];
#pragma unroll
    for (int m = 0; m < 4; ++m) {
      int row = wr * 64 + m * 16 + r;
      af[m] = *(const v8s*)(As + ((row * 64 + g * 16) ^ ((r & 7) << 4)));
    }
#pragma unroll
    for (int n = 0; n < 4; ++n) {
      int row = wc * 64 + n * 16 + r;
      bf_[n] = *(const v8s*)(Bs + ((row * 64 + g * 16) ^ ((r & 7) << 4)));
    }
#pragma unroll
    for (int m = 0; m < 4; ++m)
#pragma unroll
      for (int n = 0; n < 4; ++n)
        acc[m][n] = __builtin_amdgcn_mfma_f32_16x16x32_bf16(af[m], bf_[n], acc[m][n], 0, 0, 0);
  }

#pragma unroll
  for (int n = 0; n < 4; ++n) {
    int nglob = blockIdx.y * 128 + wc * 64 + n * 16 + r;
    float bsv = bo[nglob];
#pragma unroll
    for (int m = 0; m < 4; ++m) {
#pragma unroll
      for (int i = 0; i < 4; ++i) {
        int mglob = blockIdx.x * 128 + wr * 64 + m * 16 + g * 4 + i;
        out[(size_t)mglob * DD + nglob] = acc[m][n][i] + bsv;
      }
    }
  }
}

extern "C" void kernel_launch(void* const* d_in, const int* in_sizes, int n_in,
                              void* d_out, int out_size, void* d_ws, size_t ws_size,
                              hipStream_t stream) {
  (void)in_sizes; (void)n_in; (void)out_size; (void)ws_size;
  const float* Q  = (const float*)d_in[0];
  const float* K  = (const float*)d_in[1];
  const float* V  = (const float*)d_in[2];
  const void*  M  = d_in[3];
  const float* Wq = (const float*)d_in[4];
  const float* bq = (const float*)d_in[5];
  const float* Wk = (const float*)d_in[6];
  const float* bk = (const float*)d_in[7];
  const float* Wv = (const float*)d_in[8];
  const float* bv = (const float*)d_in[9];
  const float* Wo = (const float*)d_in[10];
  const float* bo = (const float*)d_in[11];

  float* out  = (float*)d_out;
  float* soft = out + (size_t)BB * SS * DD;

  char* ws = (char*)d_ws;
  int* flag = (int*)ws;
  unsigned long long* packed = (unsigned long long*)(ws + 256);             // 1 MB
  unsigned short* WT   = (unsigned short*)(ws + 256 + 1048576);             // 8 MB
  unsigned short* qhp  = (unsigned short*)(ws + 256 + 1048576 + 8388608);   // 8 MB
  unsigned short* khp  = qhp + (size_t)BB * SS * DD;                        // 8 MB
  unsigned short* vhT  = khp + (size_t)BB * SS * DD;                        // 8 MB (transposed V heads)
  unsigned short* attn = vhT + (size_t)BB * SS * DD;                        // 8 MB

  k_detect<<<1, 256, 0, stream>>>((const unsigned*)M, flag);
  k_pack<<<BB * SS * SS / 256, 256, 0, stream>>>(M, packed, flag);
  k_wtrans<<<dim3(32, 32, 4), dim3(32, 8), 0, stream>>>(Wq, Wk, Wv, Wo, WT);
  k_proj<<<dim3(32, 8, 3), 256, 0, stream>>>(Q, K, V, WT, bq, bk, bv, qhp, khp, vhT);
  k_attn<<<dim3(SS / 16, HH, BB), 512, 0, stream>>>(qhp, khp, vhT, (const unsigned*)packed, soft, attn);
  k_oproj<<<dim3(32, 8), 256, 0, stream>>>(attn, WT, bo, out);
}